// Round 10
// baseline (2119.970 us; speedup 1.0000x reference)
//
#include <hip/hip_runtime.h>
#include <hip/hip_bf16.h>

// Model dims
#define WLEN 2048
#define EDIM 256
#define DDIM 512
#define NLAYER 4
#define NCLS 5
#define DI 1024
#define DS 64
#define DR 32
#define DC 4
#define BB 2
#define TOK (BB*WLEN)   // 4096 tokens
#define XD (DR + 2*DS)  // 160
#define CL 128          // scan chunk length (CL=64 regressed: round 9)
#define NCH (WLEN/CL)   // 16 chunks per sequence
#define LOG2E 1.44269504f

typedef __bf16 bf16x8 __attribute__((ext_vector_type(8)));
typedef float  f32x4  __attribute__((ext_vector_type(4)));

static __device__ __forceinline__ unsigned short f2bf(float f) {
    union { float f; unsigned u; } v; v.f = f;
    unsigned r = v.u + 0x7fffu + ((v.u >> 16) & 1u);   // RNE
    return (unsigned short)(r >> 16);
}

// ---------------------------------------------------------------------------
__global__ __launch_bounds__(256) void embed_k(const int* __restrict__ seq,
    const float* __restrict__ be, const float* __restrict__ pe,
    float* __restrict__ out)
{
    int idx = blockIdx.x * 256 + threadIdx.x;      // [0, TOK*EDIM)
    int e  = idx & (EDIM - 1);
    int bl = idx >> 8;
    int l  = bl & (WLEN - 1);
    int tok = seq[bl];
    out[idx] = be[tok * EDIM + e] + pe[l * EDIM + e];
}

// ---------------------------------------------------------------------------
// LayerNorm over 512 cols, one wave per row; emits bf16 (feeds m_in MFMA GEMM)
__global__ __launch_bounds__(256) void ln_k(const float* __restrict__ x,
    const float* __restrict__ g, const float* __restrict__ b,
    unsigned short* __restrict__ out)
{
    int row  = blockIdx.x * 4 + (threadIdx.x >> 6);
    int lane = threadIdx.x & 63;
    const float* xp = x + (size_t)row * DDIM;
    float v[8];
    float s = 0.f;
#pragma unroll
    for (int i = 0; i < 8; i++) { v[i] = xp[lane + 64 * i]; s += v[i]; }
#pragma unroll
    for (int off = 32; off; off >>= 1) s += __shfl_xor(s, off, 64);
    float mu = s * (1.f / 512.f);
    float s2 = 0.f;
#pragma unroll
    for (int i = 0; i < 8; i++) { float d = v[i] - mu; s2 += d * d; }
#pragma unroll
    for (int off = 32; off; off >>= 1) s2 += __shfl_xor(s2, off, 64);
    float rs = rsqrtf(s2 * (1.f / 512.f) + 1e-5f);
#pragma unroll
    for (int i = 0; i < 8; i++) {
        int c = lane + 64 * i;
        out[(size_t)row * DDIM + c] = f2bf((v[i] - mu) * rs * g[c] + b[c]);
    }
}

// ---------------------------------------------------------------------------
// Row-contiguous depthwise causal conv + bias + silu.
// xcT [DI][TOK] -> xsT [DI][TOK]. Each thread: 8 consecutive t of one d-row.
__global__ __launch_bounds__(256) void conv_t_k(const float* __restrict__ xcT,
    const float* __restrict__ cw, const float* __restrict__ cb,
    float* __restrict__ xsT)
{
    int gid  = blockIdx.x * 256 + threadIdx.x;    // [0, DI*TOK/8)
    int row  = gid >> 9;                          // d
    int col0 = (gid & 511) << 3;                  // token col, multiple of 8
    int l0   = col0 & (WLEN - 1);
    const float* src = xcT + (size_t)row * TOK + col0;
    float xw[12];
    if (l0 > 0) {
        float4 a = *(const float4*)(src - 4);
        xw[0] = a.x; xw[1] = a.y; xw[2] = a.z; xw[3] = a.w;
    } else {
        xw[0] = xw[1] = xw[2] = xw[3] = 0.f;      // causal zero-pad at seq start
    }
    float4 m0 = *(const float4*)src;
    float4 m1 = *(const float4*)(src + 4);
    xw[4] = m0.x; xw[5] = m0.y; xw[6] = m0.z; xw[7] = m0.w;
    xw[8] = m1.x; xw[9] = m1.y; xw[10] = m1.z; xw[11] = m1.w;
    float w0 = cw[row * DC + 0], w1 = cw[row * DC + 1];
    float w2 = cw[row * DC + 2], w3 = cw[row * DC + 3];
    float bias = cb[row];
    float o[8];
#pragma unroll
    for (int u = 0; u < 8; u++) {
        float a = bias;
        a = fmaf(w0, xw[u + 1], a);
        a = fmaf(w1, xw[u + 2], a);
        a = fmaf(w2, xw[u + 3], a);
        a = fmaf(w3, xw[u + 4], a);
        o[u] = a / (1.f + __expf(-a));            // silu
    }
    float* dst = xsT + (size_t)row * TOK + col0;
    *(float4*)dst       = make_float4(o[0], o[1], o[2], o[3]);
    *(float4*)(dst + 4) = make_float4(o[4], o[5], o[6], o[7]);
}

// ---------------------------------------------------------------------------
// f32 -> bf16 flat convert (weights)
__global__ __launch_bounds__(256) void f2bf_k(const float* __restrict__ in,
    unsigned short* __restrict__ out, int n)
{
    int i = blockIdx.x * 256 + threadIdx.x;
    if (i < n) out[i] = f2bf(in[i]);
}

// ---------------------------------------------------------------------------
// B/C rows of xdblT [XD][TOK] -> BC [TOK][DS][2]  (interleaved: B=+0, C=+1)
__global__ __launch_bounds__(256) void trans_BC_k(const float* __restrict__ xdblT,
    float* __restrict__ BC)
{
    __shared__ float tile[64][65];
    int bt = blockIdx.x;        // t tile
    int half = blockIdx.y;      // 0 = B, 1 = C
    int col = threadIdx.x & 63, rr = threadIdx.x >> 6;
    int srow0 = DR + half * DS;
#pragma unroll
    for (int k = 0; k < 16; k++) {
        int i = k * 4 + rr;     // s
        tile[i][col] = xdblT[(size_t)(srow0 + i) * TOK + bt * 64 + col];
    }
    __syncthreads();
#pragma unroll
    for (int k = 0; k < 16; k++) {
        int tt = k * 4 + rr;
        BC[(size_t)(bt * 64 + tt) * 128 + col * 2 + half] = tile[col][tt];
    }
}

// ---------------------------------------------------------------------------
// yT [DI][TOK] f32 -> y_bf [TOK][DI] bf16
__global__ __launch_bounds__(256) void trans_y_k(const float* __restrict__ yT,
    unsigned short* __restrict__ ybf)
{
    __shared__ float tile[64][65];
    int bt = blockIdx.x, bd = blockIdx.y, b = blockIdx.z;
    int col = threadIdx.x & 63, rr = threadIdx.x >> 6;
#pragma unroll
    for (int k = 0; k < 16; k++) {
        int i = k * 4 + rr;   // d offset
        tile[i][col] = yT[(size_t)(bd * 64 + i) * TOK + b * WLEN + bt * 64 + col];
    }
    __syncthreads();
#pragma unroll
    for (int k = 0; k < 16; k++) {
        int tt = k * 4 + rr;  // t offset
        ybf[((size_t)(b * WLEN + bt * 64 + tt)) * DI + bd * 64 + col] = f2bf(tile[col][tt]);
    }
}

// ---------------------------------------------------------------------------
// Chunked selective scan. delta/xs/z/cd on [d][t] planes (broadcast float4);
// B/C from BC [t][s][2] (lane = s, one dwordx2 per (t,lane)).
// Software-pipelined: REDUCE(n) runs after RECUR(n+1) so the LDS write->read
// hop and the serial-FMA chain overlap with independent work.
#define SU 8

#define LOADG1(T0, dlt, xv, Bt, Ct)                                      \
  {                                                                      \
    *(float4*)&dlt[0] = *(const float4*)&dRow[(T0)];                     \
    *(float4*)&dlt[4] = *(const float4*)&dRow[(T0) + 4];                 \
    *(float4*)&xv[0]  = *(const float4*)&xRow[(T0)];                     \
    *(float4*)&xv[4]  = *(const float4*)&xRow[(T0) + 4];                 \
    const float2* bc = (const float2*)(BCrow + (size_t)(T0) * 128) + lane; \
    _Pragma("unroll")                                                    \
    for (int u = 0; u < SU; u++) {                                       \
      float2 v2 = bc[u * 64];                                            \
      Bt[u] = v2.x; Ct[u] = v2.y;                                        \
    }                                                                    \
  }

// Recurrence + LDS p-write + cd prefix/store (no reduce here)
#define RECUR(T0, dlt, xv, Bt, Ct, WRED)                                 \
  {                                                                      \
    float dA[SU], cds[SU];                                               \
    _Pragma("unroll")                                                    \
    for (int u = 0; u < SU; u++) dA[u] = __expf(dlt[u] * Aa);            \
    _Pragma("unroll")                                                    \
    for (int u = 0; u < SU; u++) {                                       \
      hst = fmaf(dA[u], hst, dlt[u] * xv[u] * Bt[u]);                    \
      WRED[u * 64 + lane] = fmaf(xv[u], Dp0, hst * Ct[u]);               \
    }                                                                    \
    cds[0] = cd + dlt[0];                                                \
    _Pragma("unroll")                                                    \
    for (int u = 1; u < SU; u++) cds[u] = cds[u - 1] + dlt[u];           \
    cd = cds[SU - 1];                                                    \
    if (lane == 0) {                                                     \
      *(float4*)&cdRow[(T0)]     = make_float4(cds[0], cds[1], cds[2], cds[3]); \
      *(float4*)&cdRow[(T0) + 4] = make_float4(cds[4], cds[5], cds[6], cds[7]); \
    }                                                                    \
  }

// LDS-transpose read + tree-add + 3-stage shfl + z store
#define REDUCE(T0, WRED)                                                 \
  {                                                                      \
    float4 q0 = *(const float4*)&WRED[(lane >> 3) * 64 + (lane & 7) * 8];     \
    float4 q1 = *(const float4*)&WRED[(lane >> 3) * 64 + (lane & 7) * 8 + 4]; \
    float sred = ((q0.x + q0.y) + (q0.z + q0.w)) +                       \
                 ((q1.x + q1.y) + (q1.z + q1.w));                        \
    sred += __shfl_xor(sred, 1, 64);                                     \
    sred += __shfl_xor(sred, 2, 64);                                     \
    sred += __shfl_xor(sred, 4, 64);                                     \
    if ((lane & 7) == 0) zRow[(T0) + (lane >> 3)] = sred;                \
  }

__global__ __launch_bounds__(256) void scan1_k(
    const float* __restrict__ deltaT,   // [DI][TOK]
    const float* __restrict__ BC,       // [TOK][DS][2]
    const float* __restrict__ xsT,      // [DI][TOK]
    const float* __restrict__ A_log,    // [DI][DS]
    const float* __restrict__ Dp,       // [DI]
    float* __restrict__ zT,             // [DI][TOK]
    float* __restrict__ cdT,            // [DI][TOK]
    float* __restrict__ Hbuf,           // [2048*NCH][DS]
    float* __restrict__ Sbuf)           // [2048*NCH]
{
    __shared__ float red[4 * 2 * SU * 64];       // 2 slots per wave, 16 KB
    int wv   = threadIdx.x >> 6;
    float* w0 = red + wv * (2 * SU * 64);
    float* w1 = w0 + SU * 64;
    int wid  = blockIdx.x * 4 + wv;     // bd*NCH + c
    int lane = threadIdx.x & 63;
    int c  = wid & (NCH - 1);
    int bd = wid >> 4;
    int d  = bd & (DI - 1);
    int b  = bd >> 10;
    size_t col0 = (size_t)b * WLEN + (size_t)c * CL;
    const float* dRow  = deltaT + (size_t)d * TOK + col0;
    const float* xRow  = xsT    + (size_t)d * TOK + col0;
    const float* BCrow = BC + col0 * 128;
    float* zRow  = zT  + (size_t)d * TOK + col0;
    float* cdRow = cdT + (size_t)d * TOK + col0;
    float Aa  = -__expf(A_log[d * DS + lane]);
    float Dp0 = (lane == 0) ? Dp[d] : 0.f;
    float hst = 0.f, cd = 0.f;

    float da[SU], xa[SU], Ba[SU], Ca[SU];
    float db[SU], xb[SU], Bb[SU], Cb[SU];

    LOADG1(0, da, xa, Ba, Ca)
    LOADG1(SU, db, xb, Bb, Cb)
    RECUR(0, da, xa, Ba, Ca, w0)
    for (int t0 = 0; t0 < CL; t0 += 2 * SU) {
        if (t0 + 2 * SU < CL) LOADG1(t0 + 2 * SU, da, xa, Ba, Ca)
        RECUR(t0 + SU, db, xb, Bb, Cb, w1)
        REDUCE(t0, w0)
        if (t0 + 3 * SU < CL) LOADG1(t0 + 3 * SU, db, xb, Bb, Cb)
        if (t0 + 2 * SU < CL) RECUR(t0 + 2 * SU, da, xa, Ba, Ca, w0)
        REDUCE(t0 + SU, w1)
    }
    Hbuf[(size_t)wid * DS + lane] = hst;
    if (lane == 0) Sbuf[wid] = cd;
}

__global__ __launch_bounds__(256) void scan2_k(
    const float* __restrict__ Hbuf, const float* __restrict__ Sbuf,
    const float* __restrict__ A_log, float* __restrict__ h0buf)
{
    int bd   = blockIdx.x * 4 + (threadIdx.x >> 6);  // 0..2047
    int lane = threadIdx.x & 63;
    int d = bd & (DI - 1);
    float Aa = -__expf(A_log[d * DS + lane]);
    float h = 0.f;
#pragma unroll
    for (int c = 0; c < NCH; c++) {
        size_t i = (size_t)bd * NCH + c;
        h0buf[i * DS + lane] = h;
        h = __expf(Aa * Sbuf[i]) * h + Hbuf[i * DS + lane];
    }
}

// scan3: lane = token. corr_t = sum_s C[t,s]*exp2(K_s*cd_t)*h0_s, then gate.
static __device__ __forceinline__ float lanef(float v, int s) {
    return __uint_as_float(__builtin_amdgcn_readlane(__float_as_uint(v), s));
}

__global__ __launch_bounds__(256) void scan3_k(
    const float* __restrict__ zT,
    const float* __restrict__ cdT,
    const float* __restrict__ rT,       // [DI][TOK]
    const float* __restrict__ xdblT,    // [XD][TOK] (C rows at DR+DS)
    const float* __restrict__ A_log,
    const float* __restrict__ h0buf,
    float* __restrict__ yT)             // [DI][TOK]
{
    int wid  = blockIdx.x * 4 + (threadIdx.x >> 6);  // bd*NCH + c
    int lane = threadIdx.x & 63;
    int c  = wid & (NCH - 1);
    int bd = wid >> 4;
    int d  = bd & (DI - 1);
    int b  = bd >> 10;
    float Kv  = -__expf(A_log[d * DS + lane]) * LOG2E;   // lane as s
    float h0v = h0buf[(size_t)wid * DS + lane];          // lane as s
    size_t rowb = (size_t)d * TOK + (size_t)b * WLEN;
    const float* Cb = xdblT + (size_t)(DR + DS) * TOK + (size_t)b * WLEN;

#pragma unroll
    for (int pass = 0; pass < CL / 64; pass++) {
        int t = c * CL + pass * 64 + lane;
        float cd = cdT[rowb + t];
        float z  = zT[rowb + t];
        float r  = rT[rowb + t];
        float c0 = 0.f, c1 = 0.f, c2 = 0.f, c3 = 0.f;
#pragma unroll
        for (int s = 0; s < DS; s += 4) {
            float C0 = Cb[(size_t)(s + 0) * TOK + t];
            float C1 = Cb[(size_t)(s + 1) * TOK + t];
            float C2 = Cb[(size_t)(s + 2) * TOK + t];
            float C3 = Cb[(size_t)(s + 3) * TOK + t];
            c0 = fmaf(C0 * lanef(h0v, s + 0), exp2f(lanef(Kv, s + 0) * cd), c0);
            c1 = fmaf(C1 * lanef(h0v, s + 1), exp2f(lanef(Kv, s + 1) * cd), c1);
            c2 = fmaf(C2 * lanef(h0v, s + 2), exp2f(lanef(Kv, s + 2) * cd), c2);
            c3 = fmaf(C3 * lanef(h0v, s + 3), exp2f(lanef(Kv, s + 3) * cd), c3);
        }
        float corr = (c0 + c1) + (c2 + c3);
        float yv = (z + corr) * (r / (1.f + __expf(-r)));
        yT[rowb + t] = yv;
    }
}

// ---------------------------------------------------------------------------
// bf16 MFMA NT GEMM: 128x128 tile, BK=32, 4 waves, mfma_f32_16x16x32_bf16.
// EPI 4: C[m][n] = acc + resid  (m_out)
// EPI 5: m_in split epilogue, both halves written TRANSPOSED [n][m]:
//        n<DI -> xcT[n][m], n>=DI -> rT[n-DI][m]
template<int EPI>
__global__ __launch_bounds__(256) void gemm_bf16(
    const unsigned short* __restrict__ A,   // [M][K] bf16
    const unsigned short* __restrict__ W,   // [N][K] bf16
    const float* __restrict__ resid,
    float* __restrict__ C,
    float* __restrict__ T0buf,              // xcT (EPI5)
    float* __restrict__ T1buf,              // rT  (EPI5)
    int M, int N, int K)
{
    __shared__ unsigned short As[4 * 128 * 8];   // [kg][row][j]
    __shared__ unsigned short Bs[4 * 128 * 8];
    const int tid = threadIdx.x;
    const int bm = blockIdx.x * 128, bn = blockIdx.y * 128;
    const int l = tid & 63, w = tid >> 6;
    const int wm = (w >> 1) * 64, wn = (w & 1) * 64;
    const int srow = tid >> 1, shalf = tid & 1;
    const int kq = l >> 4, lr = l & 15;

    f32x4 acc[4][4];
#pragma unroll
    for (int i = 0; i < 4; i++)
#pragma unroll
        for (int j = 0; j < 4; j++)
            acc[i][j] = f32x4{0.f, 0.f, 0.f, 0.f};

    for (int k0 = 0; k0 < K; k0 += 32) {
        const uint4* ga = (const uint4*)(A + (size_t)(bm + srow) * K + k0 + shalf * 16);
        uint4 a0 = ga[0], a1 = ga[1];
        const uint4* gb = (const uint4*)(W + (size_t)(bn + srow) * K + k0 + shalf * 16);
        uint4 b0 = gb[0], b1 = gb[1];
        __syncthreads();
        int kg = shalf * 2;
        *(uint4*)&As[((kg    ) * 128 + srow) * 8] = a0;
        *(uint4*)&As[((kg + 1) * 128 + srow) * 8] = a1;
        *(uint4*)&Bs[((kg    ) * 128 + srow) * 8] = b0;
        *(uint4*)&Bs[((kg + 1) * 128 + srow) * 8] = b1;
        __syncthreads();
        bf16x8 av[4], bv[4];
#pragma unroll
        for (int mf = 0; mf < 4; mf++)
            av[mf] = *(const bf16x8*)&As[(kq * 128 + wm + mf * 16 + lr) * 8];
#pragma unroll
        for (int nf = 0; nf < 4; nf++)
            bv[nf] = *(const bf16x8*)&Bs[(kq * 128 + wn + nf * 16 + lr) * 8];
#pragma unroll
        for (int mf = 0; mf < 4; mf++)
#pragma unroll
            for (int nf = 0; nf < 4; nf++)
                acc[mf][nf] = __builtin_amdgcn_mfma_f32_16x16x32_bf16(
                    av[mf], bv[nf], acc[mf][nf], 0, 0, 0);
    }
#pragma unroll
    for (int mf = 0; mf < 4; mf++) {
#pragma unroll
        for (int nf = 0; nf < 4; nf++) {
            int n  = bn + wn + nf * 16 + lr;
            int m0 = bm + wm + mf * 16 + kq * 4;
            if (EPI == 5) {
                float4 val = make_float4(acc[mf][nf][0], acc[mf][nf][1],
                                         acc[mf][nf][2], acc[mf][nf][3]);
                float* dst = (n < DI) ? &T0buf[(size_t)n * TOK + m0]
                                      : &T1buf[(size_t)(n - DI) * TOK + m0];
                *(float4*)dst = val;
            } else {
#pragma unroll
                for (int r = 0; r < 4; r++) {
                    int m = m0 + r;
                    float v = acc[mf][nf][r];
                    if (EPI == 4) v += resid[(size_t)m * N + n];
                    C[(size_t)m * N + n] = v;
                }
            }
        }
    }
}

// ---------------------------------------------------------------------------
// f32 NN GEMM: C[M][N] = A[M][K] (row-major) * B[K][N] (row-major)
// EPI: 0 none, 3 softplus(+bias[m])
template<int EPI>
__global__ __launch_bounds__(256) void gemm_nn(
    const float* __restrict__ A,
    const float* __restrict__ B,
    const float* __restrict__ bias,
    float* __restrict__ C,
    int M, int N, int K)
{
    __shared__ float As[16][64];
    __shared__ float Bs[16][64];
    const int tid = threadIdx.x;
    const int tx = tid & 15, ty = tid >> 4;
    const int bm = blockIdx.x * 64, bn = blockIdx.y * 64;
    const int arow = tid >> 2, ak = (tid & 3) << 2;
    const int brow = tid & 15, bn4 = (tid >> 4) << 2;
    float acc[4][4] = {};
    for (int k0 = 0; k0 < K; k0 += 16) {
        float4 av = make_float4(0.f, 0.f, 0.f, 0.f);
        if (bm + arow < M)
            av = *(const float4*)&A[(size_t)(bm + arow) * K + k0 + ak];
        float4 bv = *(const float4*)&B[(size_t)(k0 + brow) * N + bn + bn4];
        __syncthreads();
        As[ak + 0][arow] = av.x; As[ak + 1][arow] = av.y;
        As[ak + 2][arow] = av.z; As[ak + 3][arow] = av.w;
        *(float4*)&Bs[brow][bn4] = bv;
        __syncthreads();
#pragma unroll
        for (int k = 0; k < 16; ++k) {
            float4 a = *(const float4*)&As[k][ty * 4];
            float4 w = *(const float4*)&Bs[k][tx * 4];
            float aa[4] = {a.x, a.y, a.z, a.w};
            float ww[4] = {w.x, w.y, w.z, w.w};
#pragma unroll
            for (int i = 0; i < 4; i++)
#pragma unroll
                for (int j = 0; j < 4; j++)
                    acc[i][j] = fmaf(aa[i], ww[j], acc[i][j]);
        }
        __syncthreads();
    }
#pragma unroll
    for (int i = 0; i < 4; i++) {
        int m = bm + ty * 4 + i;
        if (m >= M) continue;
        float vv[4];
#pragma unroll
        for (int j = 0; j < 4; j++) {
            float v = acc[i][j];
            if (EPI == 3) {
                v += bias[m];
                v = fmaxf(v, 0.f) + log1pf(__expf(-fabsf(v)));
            }
            vv[j] = v;
        }
        *(float4*)&C[(size_t)m * N + bn + tx * 4] = make_float4(vv[0], vv[1], vv[2], vv[3]);
    }
}

// ---------------------------------------------------------------------------
// Generic f32 NT GEMM (in-proj + head): C = A*W^T (+ epilogue)
// EPI: 1 +bias, 2 relu(+bias)
template<int EPI>
__global__ __launch_bounds__(256) void gemm_nt(
    const float* __restrict__ A, int lda,
    const float* __restrict__ W, int ldw,
    const float* __restrict__ bias,
    float* __restrict__ C, int ldc,
    int M, int N, int K)
{
    __shared__ float As[16][64];
    __shared__ float Ws[16][64];
    const int tid = threadIdx.x;
    const int tx = tid & 15;
    const int ty = tid >> 4;
    const int bm = blockIdx.x * 64;
    const int bn = blockIdx.y * 64;
    const int lr = tid >> 2;
    const int lc = (tid & 3) << 2;
    float acc[4][4] = {};
    for (int k0 = 0; k0 < K; k0 += 16) {
        float4 av = *(const float4*)(A + (size_t)(bm + lr) * lda + (k0 + lc));
        float4 wv = make_float4(0.f, 0.f, 0.f, 0.f);
        if (bn + lr < N)
            wv = *(const float4*)(W + (size_t)(bn + lr) * ldw + (k0 + lc));
        As[lc + 0][lr] = av.x; As[lc + 1][lr] = av.y;
        As[lc + 2][lr] = av.z; As[lc + 3][lr] = av.w;
        Ws[lc + 0][lr] = wv.x; Ws[lc + 1][lr] = wv.y;
        Ws[lc + 2][lr] = wv.z; Ws[lc + 3][lr] = wv.w;
        __syncthreads();
#pragma unroll
        for (int k = 0; k < 16; ++k) {
            float4 a = *(const float4*)&As[k][ty * 4];
            float4 w = *(const float4*)&Ws[k][tx * 4];
            float aa[4] = {a.x, a.y, a.z, a.w};
            float ww[4] = {w.x, w.y, w.z, w.w};
#pragma unroll
            for (int i = 0; i < 4; i++)
#pragma unroll
                for (int j = 0; j < 4; j++)
                    acc[i][j] = fmaf(aa[i], ww[j], acc[i][j]);
        }
        __syncthreads();
    }
#pragma unroll
    for (int i = 0; i < 4; i++) {
        int m = bm + ty * 4 + i;
#pragma unroll
        for (int j = 0; j < 4; j++) {
            int n = bn + tx * 4 + j;
            if (n >= N) continue;
            float v = acc[i][j];
            v += bias[n];
            if (EPI == 2) v = fmaxf(v, 0.f);
            C[(size_t)m * ldc + n] = v;
        }
    }
}

// ---------------------------------------------------------------------------
extern "C" void kernel_launch(void* const* d_in, const int* in_sizes, int n_in,
                              void* d_out, int out_size, void* d_ws, size_t ws_size,
                              hipStream_t stream)
{
    const int*   seq        = (const int*)d_in[0];
    const float* byte_embed = (const float*)d_in[1];
    const float* pos_embed  = (const float*)d_in[2];
    const float* in_w       = (const float*)d_in[3];
    const float* in_b       = (const float*)d_in[4];
    const float* ln_g       = (const float*)d_in[5];
    const float* ln_b       = (const float*)d_in[6];
    const float* m_in_w     = (const float*)d_in[7];
    const float* conv_w     = (const float*)d_in[8];
    const float* conv_b     = (const float*)d_in[9];
    const float* xp_w       = (const float*)d_in[10];
    const float* dt_w       = (const float*)d_in[11];
    const float* dt_b       = (const float*)d_in[12];
    const float* A_log      = (const float*)d_in[13];
    const float* Dp         = (const float*)d_in[14];
    const float* m_out_w    = (const float*)d_in[15];
    const float* h1_w       = (const float*)d_in[16];
    const float* h1_b       = (const float*)d_in[17];
    const float* h2_w       = (const float*)d_in[18];
    const float* h2_b       = (const float*)d_in[19];
    const float* h3_w       = (const float*)d_in[20];
    const float* h3_b       = (const float*)d_in[21];
    float* out = (float*)d_out;

    float* ws = (float*)d_ws;
    size_t off = 0;
    float* xe     = ws + off; off += (size_t)TOK * EDIM;        // 4 MB
    float* x      = ws + off; off += (size_t)TOK * DDIM;        // residual stream
    float* xcT    = ws + off; off += (size_t)DI * TOK;          // conv input, transposed
    float* xsT    = ws + off; off += (size_t)DI * TOK;          // conv out (silu), transposed
    float* xdblT  = ws + off; off += (size_t)XD * TOK;          // xp out, transposed
    float* BC     = ws + off; off += (size_t)TOK * 2 * DS;      // B/C per token (scan1)
    float* deltaT = ws + off; off += (size_t)DI * TOK;          // softplus(dt); aliased yT
    float* zT     = ws + off; off += (size_t)DI * TOK;
    float* cdT    = ws + off; off += (size_t)DI * TOK;
    float* rT     = ws + off; off += (size_t)DI * TOK;
    float* Hbuf   = ws + off; off += (size_t)BB * DI * NCH * DS;
    float* h0buf  = ws + off; off += (size_t)BB * DI * NCH * DS;
    float* Sbuf   = ws + off; off += (size_t)BB * DI * NCH;
    unsigned short* h_bf   = (unsigned short*)(ws + off); off += (size_t)TOK * DDIM / 2;
    unsigned short* y_bf   = (unsigned short*)(ws + off); off += (size_t)TOK * DI / 2;
    unsigned short* wmi_bf = (unsigned short*)(ws + off); off += (size_t)NLAYER * 2 * DI * DDIM / 2;
    unsigned short* wmo_bf = (unsigned short*)(ws + off); off += (size_t)NLAYER * DDIM * DI / 2;
    float* yT = deltaT;          // scan3 output aliases deltaT (dead after scan1)
    float* t1 = xe;              // head temps
    float* t2 = (float*)h_bf;

    // Weight conversions (every call; harness re-poisons ws)
    {
        int n1 = NLAYER * 2 * DI * DDIM;
        f2bf_k<<<(n1 + 255) / 256, 256, 0, stream>>>(m_in_w, wmi_bf, n1);
        int n2 = NLAYER * DDIM * DI;
        f2bf_k<<<(n2 + 255) / 256, 256, 0, stream>>>(m_out_w, wmo_bf, n2);
    }

    // Embed + input projection (f32)
    embed_k<<<TOK * EDIM / 256, 256, 0, stream>>>(seq, byte_embed, pos_embed, xe);
    gemm_nt<1><<<dim3(TOK/64, DDIM/64), 256, 0, stream>>>(
        xe, EDIM, in_w, EDIM, in_b, x, DDIM, TOK, DDIM, EDIM);

    for (int i = 0; i < NLAYER; i++) {
        const float* lg  = ln_g  + (size_t)i * DDIM;
        const float* lb  = ln_b  + (size_t)i * DDIM;
        const unsigned short* miw = wmi_bf + (size_t)i * 2 * DI * DDIM;
        const float* cw  = conv_w + (size_t)i * DI * DC;
        const float* cb  = conv_b + (size_t)i * DI;
        const float* xpw = xp_w  + (size_t)i * XD * DI;
        const float* dtw = dt_w  + (size_t)i * DI * DR;
        const float* dtb = dt_b  + (size_t)i * DI;
        const float* al  = A_log + (size_t)i * DI * DS;
        const float* dp  = Dp    + (size_t)i * DI;
        const unsigned short* mow = wmo_bf + (size_t)i * DDIM * DI;

        ln_k<<<TOK/4, 256, 0, stream>>>(x, lg, lb, h_bf);
        // m_in GEMM; epilogue writes xcT (conv half) and rT (gate half), transposed
        gemm_bf16<5><<<dim3(TOK/128, 2*DI/128), 256, 0, stream>>>(
            h_bf, miw, nullptr, nullptr, xcT, rT, TOK, 2*DI, DDIM);
        conv_t_k<<<(DI * TOK / 8) / 256, 256, 0, stream>>>(xcT, cw, cb, xsT);
        // xp: xdblT[j][t] = xp_w[j][:] . xsT[:][t]
        gemm_nn<0><<<dim3((XD + 63) / 64, TOK / 64), 256, 0, stream>>>(
            xpw, xsT, nullptr, xdblT, XD, TOK, DI);
        // B/C rows -> per-token interleaved BC layout for scan1
        trans_BC_k<<<dim3(TOK/64, 2), 256, 0, stream>>>(xdblT, BC);
        // dt: deltaT[d][t] = softplus(dtw[d][:] . xdblT[0:DR][t] + dtb[d])
        gemm_nn<3><<<dim3(DI / 64, TOK / 64), 256, 0, stream>>>(
            dtw, xdblT, dtb, deltaT, DI, TOK, DR);

        scan1_k<<<(BB*DI*NCH)/4, 256, 0, stream>>>(
            deltaT, BC, xsT, al, dp, zT, cdT, Hbuf, Sbuf);
        scan2_k<<<(BB*DI)/4, 256, 0, stream>>>(Hbuf, Sbuf, al, h0buf);
        scan3_k<<<(BB*DI*NCH)/4, 256, 0, stream>>>(
            zT, cdT, rT, xdblT, al, h0buf, yT);
        trans_y_k<<<dim3(WLEN/64, DI/64, BB), 256, 0, stream>>>(yT, y_bf);

        gemm_bf16<4><<<dim3(TOK/128, DDIM/128), 256, 0, stream>>>(
            y_bf, mow, x, x, nullptr, nullptr, TOK, DDIM, DI);
    }

    // Head (f32)
    gemm_nt<2><<<dim3(TOK/64, 256/64), 256, 0, stream>>>(
        x, DDIM, h1_w, DDIM, h1_b, t1, 256, TOK, 256, DDIM);
    gemm_nt<2><<<dim3(TOK/64, 2), 256, 0, stream>>>(
        t1, 256, h2_w, 256, h2_b, t2, 128, TOK, 128, 256);
    gemm_nt<1><<<dim3(TOK/64, 1), 256, 0, stream>>>(
        t2, 128, h3_w, 128, h3_b, out, NCLS, TOK, NCLS, 128);
}

// Round 11
// 1906.606 us; speedup vs baseline: 1.1119x; 1.1119x over previous
//
#include <hip/hip_runtime.h>
#include <hip/hip_bf16.h>

// Model dims
#define WLEN 2048
#define EDIM 256
#define DDIM 512
#define NLAYER 4
#define NCLS 5
#define DI 1024
#define DS 64
#define DR 32
#define DC 4
#define BB 2
#define TOK (BB*WLEN)   // 4096 tokens
#define XD (DR + 2*DS)  // 160
#define CL 128          // scan chunk length (CL=64 regressed: r9; pipelining regressed: r10)
#define NCH (WLEN/CL)   // 16 chunks per sequence
#define LOG2E 1.44269504f

typedef __bf16 bf16x8 __attribute__((ext_vector_type(8)));
typedef float  f32x4  __attribute__((ext_vector_type(4)));

static __device__ __forceinline__ unsigned short f2bf(float f) {
    union { float f; unsigned u; } v; v.f = f;
    unsigned r = v.u + 0x7fffu + ((v.u >> 16) & 1u);   // RNE
    return (unsigned short)(r >> 16);
}

// ---------------------------------------------------------------------------
__global__ __launch_bounds__(256) void embed_k(const int* __restrict__ seq,
    const float* __restrict__ be, const float* __restrict__ pe,
    float* __restrict__ out)
{
    int idx = blockIdx.x * 256 + threadIdx.x;      // [0, TOK*EDIM)
    int e  = idx & (EDIM - 1);
    int bl = idx >> 8;
    int l  = bl & (WLEN - 1);
    int tok = seq[bl];
    out[idx] = be[tok * EDIM + e] + pe[l * EDIM + e];
}

// ---------------------------------------------------------------------------
// LayerNorm over 512 cols, one wave per row; emits bf16 (feeds m_in MFMA GEMM)
__global__ __launch_bounds__(256) void ln_k(const float* __restrict__ x,
    const float* __restrict__ g, const float* __restrict__ b,
    unsigned short* __restrict__ out)
{
    int row  = blockIdx.x * 4 + (threadIdx.x >> 6);
    int lane = threadIdx.x & 63;
    const float* xp = x + (size_t)row * DDIM;
    float v[8];
    float s = 0.f;
#pragma unroll
    for (int i = 0; i < 8; i++) { v[i] = xp[lane + 64 * i]; s += v[i]; }
#pragma unroll
    for (int off = 32; off; off >>= 1) s += __shfl_xor(s, off, 64);
    float mu = s * (1.f / 512.f);
    float s2 = 0.f;
#pragma unroll
    for (int i = 0; i < 8; i++) { float d = v[i] - mu; s2 += d * d; }
#pragma unroll
    for (int off = 32; off; off >>= 1) s2 += __shfl_xor(s2, off, 64);
    float rs = rsqrtf(s2 * (1.f / 512.f) + 1e-5f);
#pragma unroll
    for (int i = 0; i < 8; i++) {
        int c = lane + 64 * i;
        out[(size_t)row * DDIM + c] = f2bf((v[i] - mu) * rs * g[c] + b[c]);
    }
}

// ---------------------------------------------------------------------------
// Row-contiguous depthwise causal conv + bias + silu.
// xcT [DI][TOK] -> xsT [DI][TOK]. Each thread: 8 consecutive t of one d-row.
__global__ __launch_bounds__(256) void conv_t_k(const float* __restrict__ xcT,
    const float* __restrict__ cw, const float* __restrict__ cb,
    float* __restrict__ xsT)
{
    int gid  = blockIdx.x * 256 + threadIdx.x;    // [0, DI*TOK/8)
    int row  = gid >> 9;                          // d
    int col0 = (gid & 511) << 3;                  // token col, multiple of 8
    int l0   = col0 & (WLEN - 1);
    const float* src = xcT + (size_t)row * TOK + col0;
    float xw[12];
    if (l0 > 0) {
        float4 a = *(const float4*)(src - 4);
        xw[0] = a.x; xw[1] = a.y; xw[2] = a.z; xw[3] = a.w;
    } else {
        xw[0] = xw[1] = xw[2] = xw[3] = 0.f;      // causal zero-pad at seq start
    }
    float4 m0 = *(const float4*)src;
    float4 m1 = *(const float4*)(src + 4);
    xw[4] = m0.x; xw[5] = m0.y; xw[6] = m0.z; xw[7] = m0.w;
    xw[8] = m1.x; xw[9] = m1.y; xw[10] = m1.z; xw[11] = m1.w;
    float w0 = cw[row * DC + 0], w1 = cw[row * DC + 1];
    float w2 = cw[row * DC + 2], w3 = cw[row * DC + 3];
    float bias = cb[row];
    float o[8];
#pragma unroll
    for (int u = 0; u < 8; u++) {
        float a = bias;
        a = fmaf(w0, xw[u + 1], a);
        a = fmaf(w1, xw[u + 2], a);
        a = fmaf(w2, xw[u + 3], a);
        a = fmaf(w3, xw[u + 4], a);
        o[u] = a / (1.f + __expf(-a));            // silu
    }
    float* dst = xsT + (size_t)row * TOK + col0;
    *(float4*)dst       = make_float4(o[0], o[1], o[2], o[3]);
    *(float4*)(dst + 4) = make_float4(o[4], o[5], o[6], o[7]);
}

// ---------------------------------------------------------------------------
// f32 -> bf16 flat convert for BOTH weight tensors (one launch)
__global__ __launch_bounds__(256) void f2bf2_k(
    const float* __restrict__ in1, unsigned short* __restrict__ out1, int n1,
    const float* __restrict__ in2, unsigned short* __restrict__ out2, int n2)
{
    int i = blockIdx.x * 256 + threadIdx.x;
    if (i < n1) out1[i] = f2bf(in1[i]);
    else if (i < n1 + n2) out2[i - n1] = f2bf(in2[i - n1]);
}

// ---------------------------------------------------------------------------
// B/C rows of xdblT [XD][TOK] -> BC [TOK][128]  (B at +0, C at +64)
__global__ __launch_bounds__(256) void trans_BC_k(const float* __restrict__ xdblT,
    float* __restrict__ BC)
{
    __shared__ float tile[64][65];
    int bt = blockIdx.x;        // t tile
    int half = blockIdx.y;      // 0 = B, 1 = C
    int col = threadIdx.x & 63, rr = threadIdx.x >> 6;
    int srow0 = DR + half * DS;
#pragma unroll
    for (int k = 0; k < 16; k++) {
        int i = k * 4 + rr;     // s
        tile[i][col] = xdblT[(size_t)(srow0 + i) * TOK + bt * 64 + col];
    }
    __syncthreads();
#pragma unroll
    for (int k = 0; k < 16; k++) {
        int tt = k * 4 + rr;
        BC[(size_t)(bt * 64 + tt) * 128 + half * 64 + col] = tile[col][tt];
    }
}

// ---------------------------------------------------------------------------
// yT_bf [DI][TOK] bf16 -> y_bf [TOK][DI] bf16 (64x64 tile transpose)
__global__ __launch_bounds__(256) void trans_y_k(const unsigned short* __restrict__ yT,
    unsigned short* __restrict__ ybf)
{
    __shared__ unsigned short tile[64][72];
    int bt = blockIdx.x, bd = blockIdx.y, b = blockIdx.z;
    int col = threadIdx.x & 63, rr = threadIdx.x >> 6;
#pragma unroll
    for (int k = 0; k < 16; k++) {
        int i = k * 4 + rr;   // d offset
        tile[i][col] = yT[(size_t)(bd * 64 + i) * TOK + b * WLEN + bt * 64 + col];
    }
    __syncthreads();
#pragma unroll
    for (int k = 0; k < 16; k++) {
        int tt = k * 4 + rr;  // t offset
        ybf[((size_t)(b * WLEN + bt * 64 + tt)) * DI + bd * 64 + col] = tile[col][tt];
    }
}

// ---------------------------------------------------------------------------
// Chunked selective scan (round-8 form). delta/xs/z/cd on [d][t] planes;
// B/C from BC [t][128] (lane = s, literal-offset scalar loads).
#define SU 8

#define LOADG1(T0, dlt, xv, Bt, Ct)                                      \
  {                                                                      \
    *(float4*)&dlt[0] = *(const float4*)&dRow[(T0)];                     \
    *(float4*)&dlt[4] = *(const float4*)&dRow[(T0) + 4];                 \
    *(float4*)&xv[0]  = *(const float4*)&xRow[(T0)];                     \
    *(float4*)&xv[4]  = *(const float4*)&xRow[(T0) + 4];                 \
    const float* bc = BCrow + (size_t)(T0) * 128 + lane;                 \
    _Pragma("unroll")                                                    \
    for (int u = 0; u < SU; u++) {                                       \
      Bt[u] = bc[u * 128];                                               \
      Ct[u] = bc[u * 128 + 64];                                          \
    }                                                                    \
  }

// LDS-transpose reduction: p[u] -> wred[u][lane]; lane sums 8 contiguous of
// row (lane>>3); 3 shfl stages finish the 64-lane sum.
#define COMPG1(T0, dlt, xv, Bt, Ct)                                      \
  {                                                                      \
    float dA[SU], p[SU], cds[SU];                                        \
    _Pragma("unroll")                                                    \
    for (int u = 0; u < SU; u++) dA[u] = __expf(dlt[u] * Aa);            \
    _Pragma("unroll")                                                    \
    for (int u = 0; u < SU; u++) {                                       \
      hst = fmaf(dA[u], hst, dlt[u] * xv[u] * Bt[u]);                    \
      p[u] = fmaf(xv[u], Dp0, hst * Ct[u]);                              \
    }                                                                    \
    cds[0] = cd + dlt[0];                                                \
    _Pragma("unroll")                                                    \
    for (int u = 1; u < SU; u++) cds[u] = cds[u - 1] + dlt[u];           \
    cd = cds[SU - 1];                                                    \
    if (lane == 0) {                                                     \
      *(float4*)&cdRow[(T0)]     = make_float4(cds[0], cds[1], cds[2], cds[3]); \
      *(float4*)&cdRow[(T0) + 4] = make_float4(cds[4], cds[5], cds[6], cds[7]); \
    }                                                                    \
    _Pragma("unroll")                                                    \
    for (int u = 0; u < SU; u++) wred[u * 64 + lane] = p[u];             \
    float4 q0 = *(const float4*)&wred[(lane >> 3) * 64 + (lane & 7) * 8];     \
    float4 q1 = *(const float4*)&wred[(lane >> 3) * 64 + (lane & 7) * 8 + 4]; \
    float sred = ((q0.x + q0.y) + (q0.z + q0.w)) +                       \
                 ((q1.x + q1.y) + (q1.z + q1.w));                        \
    sred += __shfl_xor(sred, 1, 64);                                     \
    sred += __shfl_xor(sred, 2, 64);                                     \
    sred += __shfl_xor(sred, 4, 64);                                     \
    if ((lane & 7) == 0) zRow[(T0) + (lane >> 3)] = sred;                \
  }

__global__ __launch_bounds__(256) void scan1_k(
    const float* __restrict__ deltaT,   // [DI][TOK]
    const float* __restrict__ BC,       // [TOK][128]
    const float* __restrict__ xsT,      // [DI][TOK]
    const float* __restrict__ A_log,    // [DI][DS]
    const float* __restrict__ Dp,       // [DI]
    float* __restrict__ zT,             // [DI][TOK]
    float* __restrict__ cdT,            // [DI][TOK]
    float* __restrict__ Hbuf,           // [2048*NCH][DS]
    float* __restrict__ Sbuf)           // [2048*NCH]
{
    __shared__ float red[4 * SU * 64];
    int wv   = threadIdx.x >> 6;
    float* wred = red + wv * (SU * 64);
    int wid  = blockIdx.x * 4 + wv;     // bd*NCH + c
    int lane = threadIdx.x & 63;
    int c  = wid & (NCH - 1);
    int bd = wid >> 4;
    int d  = bd & (DI - 1);
    int b  = bd >> 10;
    size_t col0 = (size_t)b * WLEN + (size_t)c * CL;
    const float* dRow  = deltaT + (size_t)d * TOK + col0;
    const float* xRow  = xsT    + (size_t)d * TOK + col0;
    const float* BCrow = BC + col0 * 128;
    float* zRow  = zT  + (size_t)d * TOK + col0;
    float* cdRow = cdT + (size_t)d * TOK + col0;
    float Aa  = -__expf(A_log[d * DS + lane]);
    float Dp0 = (lane == 0) ? Dp[d] : 0.f;
    float hst = 0.f, cd = 0.f;

    float da[SU], xa[SU], Ba[SU], Ca[SU];
    float db[SU], xb[SU], Bb[SU], Cb[SU];

    LOADG1(0, da, xa, Ba, Ca)
    for (int t0 = 0; t0 < CL; t0 += 2 * SU) {
        LOADG1(t0 + SU, db, xb, Bb, Cb)
        COMPG1(t0, da, xa, Ba, Ca)
        if (t0 + 2 * SU < CL)
            LOADG1(t0 + 2 * SU, da, xa, Ba, Ca)
        COMPG1(t0 + SU, db, xb, Bb, Cb)
    }
    Hbuf[(size_t)wid * DS + lane] = hst;
    if (lane == 0) Sbuf[wid] = cd;
}

__global__ __launch_bounds__(256) void scan2_k(
    const float* __restrict__ Hbuf, const float* __restrict__ Sbuf,
    const float* __restrict__ A_log, float* __restrict__ h0buf)
{
    int bd   = blockIdx.x * 4 + (threadIdx.x >> 6);  // 0..2047
    int lane = threadIdx.x & 63;
    int d = bd & (DI - 1);
    float Aa = -__expf(A_log[d * DS + lane]);
    float h = 0.f;
#pragma unroll
    for (int c = 0; c < NCH; c++) {
        size_t i = (size_t)bd * NCH + c;
        h0buf[i * DS + lane] = h;
        h = __expf(Aa * Sbuf[i]) * h + Hbuf[i * DS + lane];
    }
}

// scan3: lane = token. corr_t = sum_s C[t,s]*exp2(K_s*cd_t)*h0_s, then gate.
// Emits bf16 (y is bf16-rounded before m_out anyway).
static __device__ __forceinline__ float lanef(float v, int s) {
    return __uint_as_float(__builtin_amdgcn_readlane(__float_as_uint(v), s));
}

__global__ __launch_bounds__(256) void scan3_k(
    const float* __restrict__ zT,
    const float* __restrict__ cdT,
    const float* __restrict__ rT,       // [DI][TOK]
    const float* __restrict__ xdblT,    // [XD][TOK] (C rows at DR+DS)
    const float* __restrict__ A_log,
    const float* __restrict__ h0buf,
    unsigned short* __restrict__ yT)    // [DI][TOK] bf16
{
    int wid  = blockIdx.x * 4 + (threadIdx.x >> 6);  // bd*NCH + c
    int lane = threadIdx.x & 63;
    int c  = wid & (NCH - 1);
    int bd = wid >> 4;
    int d  = bd & (DI - 1);
    int b  = bd >> 10;
    float Kv  = -__expf(A_log[d * DS + lane]) * LOG2E;   // lane as s
    float h0v = h0buf[(size_t)wid * DS + lane];          // lane as s
    size_t rowb = (size_t)d * TOK + (size_t)b * WLEN;
    const float* Cb = xdblT + (size_t)(DR + DS) * TOK + (size_t)b * WLEN;

#pragma unroll
    for (int pass = 0; pass < CL / 64; pass++) {
        int t = c * CL + pass * 64 + lane;
        float cd = cdT[rowb + t];
        float z  = zT[rowb + t];
        float r  = rT[rowb + t];
        float c0 = 0.f, c1 = 0.f, c2 = 0.f, c3 = 0.f;
#pragma unroll
        for (int s = 0; s < DS; s += 4) {
            float C0 = Cb[(size_t)(s + 0) * TOK + t];
            float C1 = Cb[(size_t)(s + 1) * TOK + t];
            float C2 = Cb[(size_t)(s + 2) * TOK + t];
            float C3 = Cb[(size_t)(s + 3) * TOK + t];
            c0 = fmaf(C0 * lanef(h0v, s + 0), exp2f(lanef(Kv, s + 0) * cd), c0);
            c1 = fmaf(C1 * lanef(h0v, s + 1), exp2f(lanef(Kv, s + 1) * cd), c1);
            c2 = fmaf(C2 * lanef(h0v, s + 2), exp2f(lanef(Kv, s + 2) * cd), c2);
            c3 = fmaf(C3 * lanef(h0v, s + 3), exp2f(lanef(Kv, s + 3) * cd), c3);
        }
        float corr = (c0 + c1) + (c2 + c3);
        float yv = (z + corr) * (r / (1.f + __expf(-r)));
        yT[rowb + t] = f2bf(yv);
    }
}

// ---------------------------------------------------------------------------
// bf16 MFMA NT GEMM: 128x128 tile, BK=32, 4 waves, mfma_f32_16x16x32_bf16.
// EPI 4: C[m][n] = acc + resid  (m_out)
// EPI 5: m_in split epilogue, both halves written TRANSPOSED [n][m]:
//        n<DI -> xcT[n][m], n>=DI -> rT[n-DI][m]
template<int EPI>
__global__ __launch_bounds__(256) void gemm_bf16(
    const unsigned short* __restrict__ A,   // [M][K] bf16
    const unsigned short* __restrict__ W,   // [N][K] bf16
    const float* __restrict__ resid,
    float* __restrict__ C,
    float* __restrict__ T0buf,              // xcT (EPI5)
    float* __restrict__ T1buf,              // rT  (EPI5)
    int M, int N, int K)
{
    __shared__ unsigned short As[4 * 128 * 8];   // [kg][row][j]
    __shared__ unsigned short Bs[4 * 128 * 8];
    const int tid = threadIdx.x;
    const int bm = blockIdx.x * 128, bn = blockIdx.y * 128;
    const int l = tid & 63, w = tid >> 6;
    const int wm = (w >> 1) * 64, wn = (w & 1) * 64;
    const int srow = tid >> 1, shalf = tid & 1;
    const int kq = l >> 4, lr = l & 15;

    f32x4 acc[4][4];
#pragma unroll
    for (int i = 0; i < 4; i++)
#pragma unroll
        for (int j = 0; j < 4; j++)
            acc[i][j] = f32x4{0.f, 0.f, 0.f, 0.f};

    for (int k0 = 0; k0 < K; k0 += 32) {
        const uint4* ga = (const uint4*)(A + (size_t)(bm + srow) * K + k0 + shalf * 16);
        uint4 a0 = ga[0], a1 = ga[1];
        const uint4* gb = (const uint4*)(W + (size_t)(bn + srow) * K + k0 + shalf * 16);
        uint4 b0 = gb[0], b1 = gb[1];
        __syncthreads();
        int kg = shalf * 2;
        *(uint4*)&As[((kg    ) * 128 + srow) * 8] = a0;
        *(uint4*)&As[((kg + 1) * 128 + srow) * 8] = a1;
        *(uint4*)&Bs[((kg    ) * 128 + srow) * 8] = b0;
        *(uint4*)&Bs[((kg + 1) * 128 + srow) * 8] = b1;
        __syncthreads();
        bf16x8 av[4], bv[4];
#pragma unroll
        for (int mf = 0; mf < 4; mf++)
            av[mf] = *(const bf16x8*)&As[(kq * 128 + wm + mf * 16 + lr) * 8];
#pragma unroll
        for (int nf = 0; nf < 4; nf++)
            bv[nf] = *(const bf16x8*)&Bs[(kq * 128 + wn + nf * 16 + lr) * 8];
#pragma unroll
        for (int mf = 0; mf < 4; mf++)
#pragma unroll
            for (int nf = 0; nf < 4; nf++)
                acc[mf][nf] = __builtin_amdgcn_mfma_f32_16x16x32_bf16(
                    av[mf], bv[nf], acc[mf][nf], 0, 0, 0);
    }
#pragma unroll
    for (int mf = 0; mf < 4; mf++) {
#pragma unroll
        for (int nf = 0; nf < 4; nf++) {
            int n  = bn + wn + nf * 16 + lr;
            int m0 = bm + wm + mf * 16 + kq * 4;
            if (EPI == 5) {
                float4 val = make_float4(acc[mf][nf][0], acc[mf][nf][1],
                                         acc[mf][nf][2], acc[mf][nf][3]);
                float* dst = (n < DI) ? &T0buf[(size_t)n * TOK + m0]
                                      : &T1buf[(size_t)(n - DI) * TOK + m0];
                *(float4*)dst = val;
            } else {
#pragma unroll
                for (int r = 0; r < 4; r++) {
                    int m = m0 + r;
                    float v = acc[mf][nf][r];
                    if (EPI == 4) v += resid[(size_t)m * N + n];
                    C[(size_t)m * N + n] = v;
                }
            }
        }
    }
}

// ---------------------------------------------------------------------------
// f32 NN GEMM: C[M][N] = A[M][K] (row-major) * B[K][N] (row-major)
// EPI: 0 none, 3 softplus(+bias[m])
template<int EPI>
__global__ __launch_bounds__(256) void gemm_nn(
    const float* __restrict__ A,
    const float* __restrict__ B,
    const float* __restrict__ bias,
    float* __restrict__ C,
    int M, int N, int K)
{
    __shared__ float As[16][64];
    __shared__ float Bs[16][64];
    const int tid = threadIdx.x;
    const int tx = tid & 15, ty = tid >> 4;
    const int bm = blockIdx.x * 64, bn = blockIdx.y * 64;
    const int arow = tid >> 2, ak = (tid & 3) << 2;
    const int brow = tid & 15, bn4 = (tid >> 4) << 2;
    float acc[4][4] = {};
    for (int k0 = 0; k0 < K; k0 += 16) {
        float4 av = make_float4(0.f, 0.f, 0.f, 0.f);
        if (bm + arow < M)
            av = *(const float4*)&A[(size_t)(bm + arow) * K + k0 + ak];
        float4 bv = *(const float4*)&B[(size_t)(k0 + brow) * N + bn + bn4];
        __syncthreads();
        As[ak + 0][arow] = av.x; As[ak + 1][arow] = av.y;
        As[ak + 2][arow] = av.z; As[ak + 3][arow] = av.w;
        *(float4*)&Bs[brow][bn4] = bv;
        __syncthreads();
#pragma unroll
        for (int k = 0; k < 16; ++k) {
            float4 a = *(const float4*)&As[k][ty * 4];
            float4 w = *(const float4*)&Bs[k][tx * 4];
            float aa[4] = {a.x, a.y, a.z, a.w};
            float ww[4] = {w.x, w.y, w.z, w.w};
#pragma unroll
            for (int i = 0; i < 4; i++)
#pragma unroll
                for (int j = 0; j < 4; j++)
                    acc[i][j] = fmaf(aa[i], ww[j], acc[i][j]);
        }
        __syncthreads();
    }
#pragma unroll
    for (int i = 0; i < 4; i++) {
        int m = bm + ty * 4 + i;
        if (m >= M) continue;
        float vv[4];
#pragma unroll
        for (int j = 0; j < 4; j++) {
            float v = acc[i][j];
            if (EPI == 3) {
                v += bias[m];
                v = fmaxf(v, 0.f) + log1pf(__expf(-fabsf(v)));
            }
            vv[j] = v;
        }
        *(float4*)&C[(size_t)m * N + bn + tx * 4] = make_float4(vv[0], vv[1], vv[2], vv[3]);
    }
}

// ---------------------------------------------------------------------------
// Generic f32 NT GEMM (in-proj + head): C = A*W^T (+ epilogue)
// EPI: 1 +bias, 2 relu(+bias)
template<int EPI>
__global__ __launch_bounds__(256) void gemm_nt(
    const float* __restrict__ A, int lda,
    const float* __restrict__ W, int ldw,
    const float* __restrict__ bias,
    float* __restrict__ C, int ldc,
    int M, int N, int K)
{
    __shared__ float As[16][64];
    __shared__ float Ws[16][64];
    const int tid = threadIdx.x;
    const int tx = tid & 15;
    const int ty = tid >> 4;
    const int bm = blockIdx.x * 64;
    const int bn = blockIdx.y * 64;
    const int lr = tid >> 2;
    const int lc = (tid & 3) << 2;
    float acc[4][4] = {};
    for (int k0 = 0; k0 < K; k0 += 16) {
        float4 av = *(const float4*)(A + (size_t)(bm + lr) * lda + (k0 + lc));
        float4 wv = make_float4(0.f, 0.f, 0.f, 0.f);
        if (bn + lr < N)
            wv = *(const float4*)(W + (size_t)(bn + lr) * ldw + (k0 + lc));
        As[lc + 0][lr] = av.x; As[lc + 1][lr] = av.y;
        As[lc + 2][lr] = av.z; As[lc + 3][lr] = av.w;
        Ws[lc + 0][lr] = wv.x; Ws[lc + 1][lr] = wv.y;
        Ws[lc + 2][lr] = wv.z; Ws[lc + 3][lr] = wv.w;
        __syncthreads();
#pragma unroll
        for (int k = 0; k < 16; ++k) {
            float4 a = *(const float4*)&As[k][ty * 4];
            float4 w = *(const float4*)&Ws[k][tx * 4];
            float aa[4] = {a.x, a.y, a.z, a.w};
            float ww[4] = {w.x, w.y, w.z, w.w};
#pragma unroll
            for (int i = 0; i < 4; i++)
#pragma unroll
                for (int j = 0; j < 4; j++)
                    acc[i][j] = fmaf(aa[i], ww[j], acc[i][j]);
        }
        __syncthreads();
    }
#pragma unroll
    for (int i = 0; i < 4; i++) {
        int m = bm + ty * 4 + i;
#pragma unroll
        for (int j = 0; j < 4; j++) {
            int n = bn + tx * 4 + j;
            if (n >= N) continue;
            float v = acc[i][j];
            v += bias[n];
            if (EPI == 2) v = fmaxf(v, 0.f);
            C[(size_t)m * ldc + n] = v;
        }
    }
}

// ---------------------------------------------------------------------------
extern "C" void kernel_launch(void* const* d_in, const int* in_sizes, int n_in,
                              void* d_out, int out_size, void* d_ws, size_t ws_size,
                              hipStream_t stream)
{
    const int*   seq        = (const int*)d_in[0];
    const float* byte_embed = (const float*)d_in[1];
    const float* pos_embed  = (const float*)d_in[2];
    const float* in_w       = (const float*)d_in[3];
    const float* in_b       = (const float*)d_in[4];
    const float* ln_g       = (const float*)d_in[5];
    const float* ln_b       = (const float*)d_in[6];
    const float* m_in_w     = (const float*)d_in[7];
    const float* conv_w     = (const float*)d_in[8];
    const float* conv_b     = (const float*)d_in[9];
    const float* xp_w       = (const float*)d_in[10];
    const float* dt_w       = (const float*)d_in[11];
    const float* dt_b       = (const float*)d_in[12];
    const float* A_log      = (const float*)d_in[13];
    const float* Dp         = (const float*)d_in[14];
    const float* m_out_w    = (const float*)d_in[15];
    const float* h1_w       = (const float*)d_in[16];
    const float* h1_b       = (const float*)d_in[17];
    const float* h2_w       = (const float*)d_in[18];
    const float* h2_b       = (const float*)d_in[19];
    const float* h3_w       = (const float*)d_in[20];
    const float* h3_b       = (const float*)d_in[21];
    float* out = (float*)d_out;

    float* ws = (float*)d_ws;
    size_t off = 0;
    float* xe     = ws + off; off += (size_t)TOK * EDIM;        // 4 MB
    float* x      = ws + off; off += (size_t)TOK * DDIM;        // residual stream
    float* xcT    = ws + off; off += (size_t)DI * TOK;          // conv input, transposed
    float* xsT    = ws + off; off += (size_t)DI * TOK;          // conv out (silu), transposed
    float* xdblT  = ws + off; off += (size_t)XD * TOK;          // xp out, transposed
    float* BC     = ws + off; off += (size_t)TOK * 2 * DS;      // B/C per token (scan1)
    float* deltaT = ws + off; off += (size_t)DI * TOK;          // softplus(dt)
    float* zT     = ws + off; off += (size_t)DI * TOK;
    float* cdT    = ws + off; off += (size_t)DI * TOK;
    float* rT     = ws + off; off += (size_t)DI * TOK;
    float* Hbuf   = ws + off; off += (size_t)BB * DI * NCH * DS;
    float* h0buf  = ws + off; off += (size_t)BB * DI * NCH * DS;
    float* Sbuf   = ws + off; off += (size_t)BB * DI * NCH;
    unsigned short* h_bf   = (unsigned short*)(ws + off); off += (size_t)TOK * DDIM / 2;
    unsigned short* y_bf   = (unsigned short*)(ws + off); off += (size_t)TOK * DI / 2;
    unsigned short* wmi_bf = (unsigned short*)(ws + off); off += (size_t)NLAYER * 2 * DI * DDIM / 2;
    unsigned short* wmo_bf = (unsigned short*)(ws + off); off += (size_t)NLAYER * DDIM * DI / 2;
    unsigned short* yT_bf = (unsigned short*)deltaT;  // scan3 bf16 out aliases deltaT (dead after scan1)
    float* t1 = xe;              // head temps
    float* t2 = (float*)h_bf;

    // Weight conversions (one launch; harness re-poisons ws every call)
    {
        int n1 = NLAYER * 2 * DI * DDIM;
        int n2 = NLAYER * DDIM * DI;
        f2bf2_k<<<(n1 + n2 + 255) / 256, 256, 0, stream>>>(
            m_in_w, wmi_bf, n1, m_out_w, wmo_bf, n2);
    }

    // Embed + input projection (f32)
    embed_k<<<TOK * EDIM / 256, 256, 0, stream>>>(seq, byte_embed, pos_embed, xe);
    gemm_nt<1><<<dim3(TOK/64, DDIM/64), 256, 0, stream>>>(
        xe, EDIM, in_w, EDIM, in_b, x, DDIM, TOK, DDIM, EDIM);

    for (int i = 0; i < NLAYER; i++) {
        const float* lg  = ln_g  + (size_t)i * DDIM;
        const float* lb  = ln_b  + (size_t)i * DDIM;
        const unsigned short* miw = wmi_bf + (size_t)i * 2 * DI * DDIM;
        const float* cw  = conv_w + (size_t)i * DI * DC;
        const float* cb  = conv_b + (size_t)i * DI;
        const float* xpw = xp_w  + (size_t)i * XD * DI;
        const float* dtw = dt_w  + (size_t)i * DI * DR;
        const float* dtb = dt_b  + (size_t)i * DI;
        const float* al  = A_log + (size_t)i * DI * DS;
        const float* dp  = Dp    + (size_t)i * DI;
        const unsigned short* mow = wmo_bf + (size_t)i * DDIM * DI;

        ln_k<<<TOK/4, 256, 0, stream>>>(x, lg, lb, h_bf);
        // m_in GEMM; epilogue writes xcT (conv half) and rT (gate half), transposed
        gemm_bf16<5><<<dim3(TOK/128, 2*DI/128), 256, 0, stream>>>(
            h_bf, miw, nullptr, nullptr, xcT, rT, TOK, 2*DI, DDIM);
        conv_t_k<<<(DI * TOK / 8) / 256, 256, 0, stream>>>(xcT, cw, cb, xsT);
        // xp: xdblT[j][t] = xp_w[j][:] . xsT[:][t]
        gemm_nn<0><<<dim3((XD + 63) / 64, TOK / 64), 256, 0, stream>>>(
            xpw, xsT, nullptr, xdblT, XD, TOK, DI);
        // B/C rows -> per-token BC layout for scan1
        trans_BC_k<<<dim3(TOK/64, 2), 256, 0, stream>>>(xdblT, BC);
        // dt: deltaT[d][t] = softplus(dtw[d][:] . xdblT[0:DR][t] + dtb[d])
        gemm_nn<3><<<dim3(DI / 64, TOK / 64), 256, 0, stream>>>(
            dtw, xdblT, dtb, deltaT, DI, TOK, DR);

        scan1_k<<<(BB*DI*NCH)/4, 256, 0, stream>>>(
            deltaT, BC, xsT, al, dp, zT, cdT, Hbuf, Sbuf);
        scan2_k<<<(BB*DI)/4, 256, 0, stream>>>(Hbuf, Sbuf, al, h0buf);
        scan3_k<<<(BB*DI*NCH)/4, 256, 0, stream>>>(
            zT, cdT, rT, xdblT, al, h0buf, yT_bf);
        trans_y_k<<<dim3(WLEN/64, DI/64, BB), 256, 0, stream>>>(yT_bf, y_bf);

        gemm_bf16<4><<<dim3(TOK/128, DDIM/128), 256, 0, stream>>>(
            y_bf, mow, x, x, nullptr, nullptr, TOK, DDIM, DI);
    }

    // Head (f32)
    gemm_nt<2><<<dim3(TOK/64, 256/64), 256, 0, stream>>>(
        x, DDIM, h1_w, DDIM, h1_b, t1, 256, TOK, 256, DDIM);
    gemm_nt<2><<<dim3(TOK/64, 2), 256, 0, stream>>>(
        t1, 256, h2_w, 256, h2_b, t2, 128, TOK, 128, 256);
    gemm_nt<1><<<dim3(TOK/64, 1), 256, 0, stream>>>(
        t2, 128, h3_w, 128, h3_b, out, NCLS, TOK, NCLS, 128);
}

// Round 12
// 1776.130 us; speedup vs baseline: 1.1936x; 1.0735x over previous
//
#include <hip/hip_runtime.h>
#include <hip/hip_bf16.h>

// Model dims
#define WLEN 2048
#define EDIM 256
#define DDIM 512
#define NLAYER 4
#define NCLS 5
#define DI 1024
#define DS 64
#define DR 32
#define DC 4
#define BB 2
#define TOK (BB*WLEN)   // 4096 tokens
#define XD (DR + 2*DS)  // 160
#define CL 128          // scan chunk length (CL=64 regressed r9; pipelining regressed r10)
#define NCH (WLEN/CL)   // 16 chunks per sequence
#define LOG2E 1.44269504f

typedef __bf16 bf16x8 __attribute__((ext_vector_type(8)));
typedef float  f32x4  __attribute__((ext_vector_type(4)));

static __device__ __forceinline__ unsigned short f2bf(float f) {
    union { float f; unsigned u; } v; v.f = f;
    unsigned r = v.u + 0x7fffu + ((v.u >> 16) & 1u);   // RNE
    return (unsigned short)(r >> 16);
}

// ---------------------------------------------------------------------------
__global__ __launch_bounds__(256) void embed_k(const int* __restrict__ seq,
    const float* __restrict__ be, const float* __restrict__ pe,
    float* __restrict__ out)
{
    int idx = blockIdx.x * 256 + threadIdx.x;      // [0, TOK*EDIM)
    int e  = idx & (EDIM - 1);
    int bl = idx >> 8;
    int l  = bl & (WLEN - 1);
    int tok = seq[bl];
    out[idx] = be[tok * EDIM + e] + pe[l * EDIM + e];
}

// ---------------------------------------------------------------------------
// LayerNorm over 512 cols, one wave per row; emits bf16 (feeds m_in MFMA GEMM)
__global__ __launch_bounds__(256) void ln_k(const float* __restrict__ x,
    const float* __restrict__ g, const float* __restrict__ b,
    unsigned short* __restrict__ out)
{
    int row  = blockIdx.x * 4 + (threadIdx.x >> 6);
    int lane = threadIdx.x & 63;
    const float* xp = x + (size_t)row * DDIM;
    float v[8];
    float s = 0.f;
#pragma unroll
    for (int i = 0; i < 8; i++) { v[i] = xp[lane + 64 * i]; s += v[i]; }
#pragma unroll
    for (int off = 32; off; off >>= 1) s += __shfl_xor(s, off, 64);
    float mu = s * (1.f / 512.f);
    float s2 = 0.f;
#pragma unroll
    for (int i = 0; i < 8; i++) { float d = v[i] - mu; s2 += d * d; }
#pragma unroll
    for (int off = 32; off; off >>= 1) s2 += __shfl_xor(s2, off, 64);
    float rs = rsqrtf(s2 * (1.f / 512.f) + 1e-5f);
#pragma unroll
    for (int i = 0; i < 8; i++) {
        int c = lane + 64 * i;
        out[(size_t)row * DDIM + c] = f2bf((v[i] - mu) * rs * g[c] + b[c]);
    }
}

// ---------------------------------------------------------------------------
// Row-contiguous depthwise causal conv + bias + silu.
// xcT [DI][TOK] -> xsT [DI][TOK]. Each thread: 8 consecutive t of one d-row.
__global__ __launch_bounds__(256) void conv_t_k(const float* __restrict__ xcT,
    const float* __restrict__ cw, const float* __restrict__ cb,
    float* __restrict__ xsT)
{
    int gid  = blockIdx.x * 256 + threadIdx.x;    // [0, DI*TOK/8)
    int row  = gid >> 9;                          // d
    int col0 = (gid & 511) << 3;                  // token col, multiple of 8
    int l0   = col0 & (WLEN - 1);
    const float* src = xcT + (size_t)row * TOK + col0;
    float xw[12];
    if (l0 > 0) {
        float4 a = *(const float4*)(src - 4);
        xw[0] = a.x; xw[1] = a.y; xw[2] = a.z; xw[3] = a.w;
    } else {
        xw[0] = xw[1] = xw[2] = xw[3] = 0.f;      // causal zero-pad at seq start
    }
    float4 m0 = *(const float4*)src;
    float4 m1 = *(const float4*)(src + 4);
    xw[4] = m0.x; xw[5] = m0.y; xw[6] = m0.z; xw[7] = m0.w;
    xw[8] = m1.x; xw[9] = m1.y; xw[10] = m1.z; xw[11] = m1.w;
    float w0 = cw[row * DC + 0], w1 = cw[row * DC + 1];
    float w2 = cw[row * DC + 2], w3 = cw[row * DC + 3];
    float bias = cb[row];
    float o[8];
#pragma unroll
    for (int u = 0; u < 8; u++) {
        float a = bias;
        a = fmaf(w0, xw[u + 1], a);
        a = fmaf(w1, xw[u + 2], a);
        a = fmaf(w2, xw[u + 3], a);
        a = fmaf(w3, xw[u + 4], a);
        o[u] = a / (1.f + __expf(-a));            // silu
    }
    float* dst = xsT + (size_t)row * TOK + col0;
    *(float4*)dst       = make_float4(o[0], o[1], o[2], o[3]);
    *(float4*)(dst + 4) = make_float4(o[4], o[5], o[6], o[7]);
}

// ---------------------------------------------------------------------------
// f32 -> bf16 flat convert for BOTH weight tensors (one launch)
__global__ __launch_bounds__(256) void f2bf2_k(
    const float* __restrict__ in1, unsigned short* __restrict__ out1, int n1,
    const float* __restrict__ in2, unsigned short* __restrict__ out2, int n2)
{
    int i = blockIdx.x * 256 + threadIdx.x;
    if (i < n1) out1[i] = f2bf(in1[i]);
    else if (i < n1 + n2) out2[i - n1] = f2bf(in2[i - n1]);
}

// ---------------------------------------------------------------------------
// yT_bf [DI][TOK] bf16 -> y_bf [TOK][DI] bf16 (64x64 tile transpose)
__global__ __launch_bounds__(256) void trans_y_k(const unsigned short* __restrict__ yT,
    unsigned short* __restrict__ ybf)
{
    __shared__ unsigned short tile[64][72];
    int bt = blockIdx.x, bd = blockIdx.y, b = blockIdx.z;
    int col = threadIdx.x & 63, rr = threadIdx.x >> 6;
#pragma unroll
    for (int k = 0; k < 16; k++) {
        int i = k * 4 + rr;   // d offset
        tile[i][col] = yT[(size_t)(bd * 64 + i) * TOK + b * WLEN + bt * 64 + col];
    }
    __syncthreads();
#pragma unroll
    for (int k = 0; k < 16; k++) {
        int tt = k * 4 + rr;  // t offset
        ybf[((size_t)(b * WLEN + bt * 64 + tt)) * DI + bd * 64 + col] = tile[col][tt];
    }
}

// ---------------------------------------------------------------------------
// Chunked selective scan. Block = 4 waves = 4 consecutive channels x SAME
// chunk; BC for the chunk staged in LDS (two 32KB halves) and shared by all
// waves. delta/xs/z/cd on [d][t] planes (broadcast float4).
#define SU 8

#define LOADDX(T0, dlt, xv)                                              \
  {                                                                      \
    *(float4*)&dlt[0] = *(const float4*)&dRow[(T0)];                     \
    *(float4*)&dlt[4] = *(const float4*)&dRow[(T0) + 4];                 \
    *(float4*)&xv[0]  = *(const float4*)&xRow[(T0)];                     \
    *(float4*)&xv[4]  = *(const float4*)&xRow[(T0) + 4];                 \
  }

// B/C from LDS; LDS-transpose reduction as in the proven r8 form.
#define COMPG1(T0, dlt, xv)                                              \
  {                                                                      \
    const float* bl = &bcs[((T0) & 63) * 128 + lane];                    \
    float Bt[SU], Ct[SU];                                                \
    _Pragma("unroll")                                                    \
    for (int u = 0; u < SU; u++) {                                       \
      Bt[u] = bl[u * 128];                                               \
      Ct[u] = bl[u * 128 + 64];                                          \
    }                                                                    \
    float dA[SU], p[SU], cds[SU];                                        \
    _Pragma("unroll")                                                    \
    for (int u = 0; u < SU; u++) dA[u] = __expf(dlt[u] * Aa);            \
    _Pragma("unroll")                                                    \
    for (int u = 0; u < SU; u++) {                                       \
      hst = fmaf(dA[u], hst, dlt[u] * xv[u] * Bt[u]);                    \
      p[u] = fmaf(xv[u], Dp0, hst * Ct[u]);                              \
    }                                                                    \
    cds[0] = cd + dlt[0];                                                \
    _Pragma("unroll")                                                    \
    for (int u = 1; u < SU; u++) cds[u] = cds[u - 1] + dlt[u];           \
    cd = cds[SU - 1];                                                    \
    if (lane == 0) {                                                     \
      *(float4*)&cdRow[(T0)]     = make_float4(cds[0], cds[1], cds[2], cds[3]); \
      *(float4*)&cdRow[(T0) + 4] = make_float4(cds[4], cds[5], cds[6], cds[7]); \
    }                                                                    \
    _Pragma("unroll")                                                    \
    for (int u = 0; u < SU; u++) wred[u * 64 + lane] = p[u];             \
    float4 q0 = *(const float4*)&wred[(lane >> 3) * 64 + (lane & 7) * 8];     \
    float4 q1 = *(const float4*)&wred[(lane >> 3) * 64 + (lane & 7) * 8 + 4]; \
    float sred = ((q0.x + q0.y) + (q0.z + q0.w)) +                       \
                 ((q1.x + q1.y) + (q1.z + q1.w));                        \
    sred += __shfl_xor(sred, 1, 64);                                     \
    sred += __shfl_xor(sred, 2, 64);                                     \
    sred += __shfl_xor(sred, 4, 64);                                     \
    if ((lane & 7) == 0) zRow[(T0) + (lane >> 3)] = sred;                \
  }

__global__ __launch_bounds__(256) void scan1_k(
    const float* __restrict__ deltaT,   // [DI][TOK]
    const float* __restrict__ BC,       // [TOK][128]  (B at +0, C at +64)
    const float* __restrict__ xsT,      // [DI][TOK]
    const float* __restrict__ A_log,    // [DI][DS]
    const float* __restrict__ Dp,       // [DI]
    float* __restrict__ zT,             // [DI][TOK]
    float* __restrict__ cdT,            // [DI][TOK]
    float* __restrict__ Hbuf,           // [2048*NCH][DS]
    float* __restrict__ Sbuf)           // [2048*NCH]
{
    __shared__ float bcs[64 * 128];              // 32 KB: one half-chunk of B/C
    __shared__ float red[4 * SU * 64];           // 8 KB
    const int tid  = threadIdx.x;
    const int wv   = tid >> 6;
    const int lane = tid & 63;
    float* wred = red + wv * (SU * 64);
    int c  = blockIdx.x & (NCH - 1);             // chunk (shared by block)
    int bd = (blockIdx.x >> 4) * 4 + wv;         // channel (per wave)
    int d  = bd & (DI - 1);
    int b  = bd >> 10;
    int wid = (bd << 4) + c;                     // bd*NCH + c
    size_t col0 = (size_t)b * WLEN + (size_t)c * CL;
    const float* dRow  = deltaT + (size_t)d * TOK + col0;
    const float* xRow  = xsT    + (size_t)d * TOK + col0;
    const float4* BCg  = (const float4*)(BC + col0 * 128);
    float* zRow  = zT  + (size_t)d * TOK + col0;
    float* cdRow = cdT + (size_t)d * TOK + col0;
    float Aa  = -__expf(A_log[d * DS + lane]);
    float Dp0 = (lane == 0) ? Dp[d] : 0.f;
    float hst = 0.f, cd = 0.f;

    float da[SU], xa[SU];
    float db[SU], xb[SU];

#pragma unroll
    for (int half = 0; half < 2; half++) {
        if (half) __syncthreads();               // prev half fully consumed
#pragma unroll
        for (int k = 0; k < 8; k++)              // stage 64 t x 128 f32 = 32 KB
            ((float4*)bcs)[k * 256 + tid] = BCg[half * 2048 + k * 256 + tid];
        __syncthreads();
        int base = half * 64;
        LOADDX(base, da, xa)
        for (int t0 = base; t0 < base + 64; t0 += 2 * SU) {
            LOADDX(t0 + SU, db, xb)
            COMPG1(t0, da, xa)
            if (t0 + 2 * SU < base + 64)
                LOADDX(t0 + 2 * SU, da, xa)
            COMPG1(t0 + SU, db, xb)
        }
    }
    Hbuf[(size_t)wid * DS + lane] = hst;
    if (lane == 0) Sbuf[wid] = cd;
}

__global__ __launch_bounds__(256) void scan2_k(
    const float* __restrict__ Hbuf, const float* __restrict__ Sbuf,
    const float* __restrict__ A_log, float* __restrict__ h0buf)
{
    int bd   = blockIdx.x * 4 + (threadIdx.x >> 6);  // 0..2047
    int lane = threadIdx.x & 63;
    int d = bd & (DI - 1);
    float Aa = -__expf(A_log[d * DS + lane]);
    float h = 0.f;
#pragma unroll
    for (int c = 0; c < NCH; c++) {
        size_t i = (size_t)bd * NCH + c;
        h0buf[i * DS + lane] = h;
        h = __expf(Aa * Sbuf[i]) * h + Hbuf[i * DS + lane];
    }
}

// scan3: lane = token. corr_t = sum_s C[t,s]*exp2(K_s*cd_t)*h0_s, then gate.
// Emits bf16 (y is bf16-rounded before m_out anyway).
static __device__ __forceinline__ float lanef(float v, int s) {
    return __uint_as_float(__builtin_amdgcn_readlane(__float_as_uint(v), s));
}

__global__ __launch_bounds__(256) void scan3_k(
    const float* __restrict__ zT,
    const float* __restrict__ cdT,
    const float* __restrict__ rT,       // [DI][TOK]
    const float* __restrict__ xdblT,    // [XD][TOK] (C rows at DR+DS)
    const float* __restrict__ A_log,
    const float* __restrict__ h0buf,
    unsigned short* __restrict__ yT)    // [DI][TOK] bf16
{
    int wid  = blockIdx.x * 4 + (threadIdx.x >> 6);  // bd*NCH + c
    int lane = threadIdx.x & 63;
    int c  = wid & (NCH - 1);
    int bd = wid >> 4;
    int d  = bd & (DI - 1);
    int b  = bd >> 10;
    float Kv  = -__expf(A_log[d * DS + lane]) * LOG2E;   // lane as s
    float h0v = h0buf[(size_t)wid * DS + lane];          // lane as s
    size_t rowb = (size_t)d * TOK + (size_t)b * WLEN;
    const float* Cb = xdblT + (size_t)(DR + DS) * TOK + (size_t)b * WLEN;

#pragma unroll
    for (int pass = 0; pass < CL / 64; pass++) {
        int t = c * CL + pass * 64 + lane;
        float cd = cdT[rowb + t];
        float z  = zT[rowb + t];
        float r  = rT[rowb + t];
        float c0 = 0.f, c1 = 0.f, c2 = 0.f, c3 = 0.f;
#pragma unroll
        for (int s = 0; s < DS; s += 4) {
            float C0 = Cb[(size_t)(s + 0) * TOK + t];
            float C1 = Cb[(size_t)(s + 1) * TOK + t];
            float C2 = Cb[(size_t)(s + 2) * TOK + t];
            float C3 = Cb[(size_t)(s + 3) * TOK + t];
            c0 = fmaf(C0 * lanef(h0v, s + 0), exp2f(lanef(Kv, s + 0) * cd), c0);
            c1 = fmaf(C1 * lanef(h0v, s + 1), exp2f(lanef(Kv, s + 1) * cd), c1);
            c2 = fmaf(C2 * lanef(h0v, s + 2), exp2f(lanef(Kv, s + 2) * cd), c2);
            c3 = fmaf(C3 * lanef(h0v, s + 3), exp2f(lanef(Kv, s + 3) * cd), c3);
        }
        float corr = (c0 + c1) + (c2 + c3);
        float yv = (z + corr) * (r / (1.f + __expf(-r)));
        yT[rowb + t] = f2bf(yv);
    }
}

// ---------------------------------------------------------------------------
// bf16 MFMA NT GEMM: 128x128 tile, BK=32, 4 waves, mfma_f32_16x16x32_bf16.
// EPI 4: C[m][n] = acc + resid  (m_out)
// EPI 5: m_in split epilogue, both halves written TRANSPOSED [n][m]:
//        n<DI -> xcT[n][m], n>=DI -> rT[n-DI][m]
template<int EPI>
__global__ __launch_bounds__(256) void gemm_bf16(
    const unsigned short* __restrict__ A,   // [M][K] bf16
    const unsigned short* __restrict__ W,   // [N][K] bf16
    const float* __restrict__ resid,
    float* __restrict__ C,
    float* __restrict__ T0buf,              // xcT (EPI5)
    float* __restrict__ T1buf,              // rT  (EPI5)
    int M, int N, int K)
{
    __shared__ unsigned short As[4 * 128 * 8];   // [kg][row][j]
    __shared__ unsigned short Bs[4 * 128 * 8];
    const int tid = threadIdx.x;
    const int bm = blockIdx.x * 128, bn = blockIdx.y * 128;
    const int l = tid & 63, w = tid >> 6;
    const int wm = (w >> 1) * 64, wn = (w & 1) * 64;
    const int srow = tid >> 1, shalf = tid & 1;
    const int kq = l >> 4, lr = l & 15;

    f32x4 acc[4][4];
#pragma unroll
    for (int i = 0; i < 4; i++)
#pragma unroll
        for (int j = 0; j < 4; j++)
            acc[i][j] = f32x4{0.f, 0.f, 0.f, 0.f};

    for (int k0 = 0; k0 < K; k0 += 32) {
        const uint4* ga = (const uint4*)(A + (size_t)(bm + srow) * K + k0 + shalf * 16);
        uint4 a0 = ga[0], a1 = ga[1];
        const uint4* gb = (const uint4*)(W + (size_t)(bn + srow) * K + k0 + shalf * 16);
        uint4 b0 = gb[0], b1 = gb[1];
        __syncthreads();
        int kg = shalf * 2;
        *(uint4*)&As[((kg    ) * 128 + srow) * 8] = a0;
        *(uint4*)&As[((kg + 1) * 128 + srow) * 8] = a1;
        *(uint4*)&Bs[((kg    ) * 128 + srow) * 8] = b0;
        *(uint4*)&Bs[((kg + 1) * 128 + srow) * 8] = b1;
        __syncthreads();
        bf16x8 av[4], bv[4];
#pragma unroll
        for (int mf = 0; mf < 4; mf++)
            av[mf] = *(const bf16x8*)&As[(kq * 128 + wm + mf * 16 + lr) * 8];
#pragma unroll
        for (int nf = 0; nf < 4; nf++)
            bv[nf] = *(const bf16x8*)&Bs[(kq * 128 + wn + nf * 16 + lr) * 8];
#pragma unroll
        for (int mf = 0; mf < 4; mf++)
#pragma unroll
            for (int nf = 0; nf < 4; nf++)
                acc[mf][nf] = __builtin_amdgcn_mfma_f32_16x16x32_bf16(
                    av[mf], bv[nf], acc[mf][nf], 0, 0, 0);
    }
#pragma unroll
    for (int mf = 0; mf < 4; mf++) {
#pragma unroll
        for (int nf = 0; nf < 4; nf++) {
            int n  = bn + wn + nf * 16 + lr;
            int m0 = bm + wm + mf * 16 + kq * 4;
            if (EPI == 5) {
                float4 val = make_float4(acc[mf][nf][0], acc[mf][nf][1],
                                         acc[mf][nf][2], acc[mf][nf][3]);
                float* dst = (n < DI) ? &T0buf[(size_t)n * TOK + m0]
                                      : &T1buf[(size_t)(n - DI) * TOK + m0];
                *(float4*)dst = val;
            } else {
#pragma unroll
                for (int r = 0; r < 4; r++) {
                    int m = m0 + r;
                    float v = acc[mf][nf][r];
                    if (EPI == 4) v += resid[(size_t)m * N + n];
                    C[(size_t)m * N + n] = v;
                }
            }
        }
    }
}

// ---------------------------------------------------------------------------
// f32 NN GEMM: C[M][N] = A[M][K] (row-major) * B[K][N] (row-major)
// EPI: 3 softplus(+bias[m]);  5 = plain + fused BC write (rows m>=DR ->
//      BCout[n*128 + (m-DR)]; B rows 32..95 -> +0..63, C rows 96..159 -> +64..127)
template<int EPI>
__global__ __launch_bounds__(256) void gemm_nn(
    const float* __restrict__ A,
    const float* __restrict__ B,
    const float* __restrict__ bias,
    float* __restrict__ C,
    float* __restrict__ BCout,
    int M, int N, int K)
{
    __shared__ float As[16][64];
    __shared__ float Bs[16][64];
    const int tid = threadIdx.x;
    const int tx = tid & 15, ty = tid >> 4;
    const int bm = blockIdx.x * 64, bn = blockIdx.y * 64;
    const int arow = tid >> 2, ak = (tid & 3) << 2;
    const int brow = tid & 15, bn4 = (tid >> 4) << 2;
    float acc[4][4] = {};
    for (int k0 = 0; k0 < K; k0 += 16) {
        float4 av = make_float4(0.f, 0.f, 0.f, 0.f);
        if (bm + arow < M)
            av = *(const float4*)&A[(size_t)(bm + arow) * K + k0 + ak];
        float4 bv = *(const float4*)&B[(size_t)(k0 + brow) * N + bn + bn4];
        __syncthreads();
        As[ak + 0][arow] = av.x; As[ak + 1][arow] = av.y;
        As[ak + 2][arow] = av.z; As[ak + 3][arow] = av.w;
        *(float4*)&Bs[brow][bn4] = bv;
        __syncthreads();
#pragma unroll
        for (int k = 0; k < 16; ++k) {
            float4 a = *(const float4*)&As[k][ty * 4];
            float4 w = *(const float4*)&Bs[k][tx * 4];
            float aa[4] = {a.x, a.y, a.z, a.w};
            float ww[4] = {w.x, w.y, w.z, w.w};
#pragma unroll
            for (int i = 0; i < 4; i++)
#pragma unroll
                for (int j = 0; j < 4; j++)
                    acc[i][j] = fmaf(aa[i], ww[j], acc[i][j]);
        }
        __syncthreads();
    }
#pragma unroll
    for (int i = 0; i < 4; i++) {
        int m = bm + ty * 4 + i;
        if (m >= M) continue;
        float vv[4];
#pragma unroll
        for (int j = 0; j < 4; j++) {
            float v = acc[i][j];
            if (EPI == 3) {
                v += bias[m];
                v = fmaxf(v, 0.f) + log1pf(__expf(-fabsf(v)));
            }
            vv[j] = v;
        }
        *(float4*)&C[(size_t)m * N + bn + tx * 4] = make_float4(vv[0], vv[1], vv[2], vv[3]);
        if (EPI == 5 && m >= DR) {
#pragma unroll
            for (int j = 0; j < 4; j++)
                BCout[(size_t)(bn + tx * 4 + j) * 128 + (m - DR)] = vv[j];
        }
    }
}

// ---------------------------------------------------------------------------
// Generic f32 NT GEMM (in-proj + head): C = A*W^T (+ epilogue)
// EPI: 1 +bias, 2 relu(+bias)
template<int EPI>
__global__ __launch_bounds__(256) void gemm_nt(
    const float* __restrict__ A, int lda,
    const float* __restrict__ W, int ldw,
    const float* __restrict__ bias,
    float* __restrict__ C, int ldc,
    int M, int N, int K)
{
    __shared__ float As[16][64];
    __shared__ float Ws[16][64];
    const int tid = threadIdx.x;
    const int tx = tid & 15;
    const int ty = tid >> 4;
    const int bm = blockIdx.x * 64;
    const int bn = blockIdx.y * 64;
    const int lr = tid >> 2;
    const int lc = (tid & 3) << 2;
    float acc[4][4] = {};
    for (int k0 = 0; k0 < K; k0 += 16) {
        float4 av = *(const float4*)(A + (size_t)(bm + lr) * lda + (k0 + lc));
        float4 wv = make_float4(0.f, 0.f, 0.f, 0.f);
        if (bn + lr < N)
            wv = *(const float4*)(W + (size_t)(bn + lr) * ldw + (k0 + lc));
        As[lc + 0][lr] = av.x; As[lc + 1][lr] = av.y;
        As[lc + 2][lr] = av.z; As[lc + 3][lr] = av.w;
        Ws[lc + 0][lr] = wv.x; Ws[lc + 1][lr] = wv.y;
        Ws[lc + 2][lr] = wv.z; Ws[lc + 3][lr] = wv.w;
        __syncthreads();
#pragma unroll
        for (int k = 0; k < 16; ++k) {
            float4 a = *(const float4*)&As[k][ty * 4];
            float4 w = *(const float4*)&Ws[k][tx * 4];
            float aa[4] = {a.x, a.y, a.z, a.w};
            float ww[4] = {w.x, w.y, w.z, w.w};
#pragma unroll
            for (int i = 0; i < 4; i++)
#pragma unroll
                for (int j = 0; j < 4; j++)
                    acc[i][j] = fmaf(aa[i], ww[j], acc[i][j]);
        }
        __syncthreads();
    }
#pragma unroll
    for (int i = 0; i < 4; i++) {
        int m = bm + ty * 4 + i;
#pragma unroll
        for (int j = 0; j < 4; j++) {
            int n = bn + tx * 4 + j;
            if (n >= N) continue;
            float v = acc[i][j];
            v += bias[n];
            if (EPI == 2) v = fmaxf(v, 0.f);
            C[(size_t)m * ldc + n] = v;
        }
    }
}

// ---------------------------------------------------------------------------
extern "C" void kernel_launch(void* const* d_in, const int* in_sizes, int n_in,
                              void* d_out, int out_size, void* d_ws, size_t ws_size,
                              hipStream_t stream)
{
    const int*   seq        = (const int*)d_in[0];
    const float* byte_embed = (const float*)d_in[1];
    const float* pos_embed  = (const float*)d_in[2];
    const float* in_w       = (const float*)d_in[3];
    const float* in_b       = (const float*)d_in[4];
    const float* ln_g       = (const float*)d_in[5];
    const float* ln_b       = (const float*)d_in[6];
    const float* m_in_w     = (const float*)d_in[7];
    const float* conv_w     = (const float*)d_in[8];
    const float* conv_b     = (const float*)d_in[9];
    const float* xp_w       = (const float*)d_in[10];
    const float* dt_w       = (const float*)d_in[11];
    const float* dt_b       = (const float*)d_in[12];
    const float* A_log      = (const float*)d_in[13];
    const float* Dp         = (const float*)d_in[14];
    const float* m_out_w    = (const float*)d_in[15];
    const float* h1_w       = (const float*)d_in[16];
    const float* h1_b       = (const float*)d_in[17];
    const float* h2_w       = (const float*)d_in[18];
    const float* h2_b       = (const float*)d_in[19];
    const float* h3_w       = (const float*)d_in[20];
    const float* h3_b       = (const float*)d_in[21];
    float* out = (float*)d_out;

    float* ws = (float*)d_ws;
    size_t off = 0;
    float* xe     = ws + off; off += (size_t)TOK * EDIM;        // 4 MB
    float* x      = ws + off; off += (size_t)TOK * DDIM;        // residual stream
    float* xcT    = ws + off; off += (size_t)DI * TOK;          // conv input, transposed
    float* xsT    = ws + off; off += (size_t)DI * TOK;          // conv out (silu), transposed
    float* xdblT  = ws + off; off += (size_t)XD * TOK;          // xp out, transposed
    float* BC     = ws + off; off += (size_t)TOK * 2 * DS;      // B/C per token (scan1)
    float* deltaT = ws + off; off += (size_t)DI * TOK;          // softplus(dt)
    float* zT     = ws + off; off += (size_t)DI * TOK;
    float* cdT    = ws + off; off += (size_t)DI * TOK;
    float* rT     = ws + off; off += (size_t)DI * TOK;
    float* Hbuf   = ws + off; off += (size_t)BB * DI * NCH * DS;
    float* h0buf  = ws + off; off += (size_t)BB * DI * NCH * DS;
    float* Sbuf   = ws + off; off += (size_t)BB * DI * NCH;
    unsigned short* h_bf   = (unsigned short*)(ws + off); off += (size_t)TOK * DDIM / 2;
    unsigned short* y_bf   = (unsigned short*)(ws + off); off += (size_t)TOK * DI / 2;
    unsigned short* wmi_bf = (unsigned short*)(ws + off); off += (size_t)NLAYER * 2 * DI * DDIM / 2;
    unsigned short* wmo_bf = (unsigned short*)(ws + off); off += (size_t)NLAYER * DDIM * DI / 2;
    unsigned short* yT_bf = (unsigned short*)deltaT;  // scan3 bf16 out aliases deltaT (dead after scan1)
    float* t1 = xe;              // head temps
    float* t2 = (float*)h_bf;

    // Weight conversions (one launch; harness re-poisons ws every call)
    {
        int n1 = NLAYER * 2 * DI * DDIM;
        int n2 = NLAYER * DDIM * DI;
        f2bf2_k<<<(n1 + n2 + 255) / 256, 256, 0, stream>>>(
            m_in_w, wmi_bf, n1, m_out_w, wmo_bf, n2);
    }

    // Embed + input projection (f32)
    embed_k<<<TOK * EDIM / 256, 256, 0, stream>>>(seq, byte_embed, pos_embed, xe);
    gemm_nt<1><<<dim3(TOK/64, DDIM/64), 256, 0, stream>>>(
        xe, EDIM, in_w, EDIM, in_b, x, DDIM, TOK, DDIM, EDIM);

    for (int i = 0; i < NLAYER; i++) {
        const float* lg  = ln_g  + (size_t)i * DDIM;
        const float* lb  = ln_b  + (size_t)i * DDIM;
        const unsigned short* miw = wmi_bf + (size_t)i * 2 * DI * DDIM;
        const float* cw  = conv_w + (size_t)i * DI * DC;
        const float* cb  = conv_b + (size_t)i * DI;
        const float* xpw = xp_w  + (size_t)i * XD * DI;
        const float* dtw = dt_w  + (size_t)i * DI * DR;
        const float* dtb = dt_b  + (size_t)i * DI;
        const float* al  = A_log + (size_t)i * DI * DS;
        const float* dp  = Dp    + (size_t)i * DI;
        const unsigned short* mow = wmo_bf + (size_t)i * DDIM * DI;

        ln_k<<<TOK/4, 256, 0, stream>>>(x, lg, lb, h_bf);
        // m_in GEMM; epilogue writes xcT (conv half) and rT (gate half), transposed
        gemm_bf16<5><<<dim3(TOK/128, 2*DI/128), 256, 0, stream>>>(
            h_bf, miw, nullptr, nullptr, xcT, rT, TOK, 2*DI, DDIM);
        conv_t_k<<<(DI * TOK / 8) / 256, 256, 0, stream>>>(xcT, cw, cb, xsT);
        // xp: xdblT[j][t] = xp_w[j][:] . xsT[:][t]; epilogue also writes BC
        gemm_nn<5><<<dim3((XD + 63) / 64, TOK / 64), 256, 0, stream>>>(
            xpw, xsT, nullptr, xdblT, BC, XD, TOK, DI);
        // dt: deltaT[d][t] = softplus(dtw[d][:] . xdblT[0:DR][t] + dtb[d])
        gemm_nn<3><<<dim3(DI / 64, TOK / 64), 256, 0, stream>>>(
            dtw, xdblT, dtb, deltaT, nullptr, DI, TOK, DR);

        scan1_k<<<(BB*DI*NCH)/4, 256, 0, stream>>>(
            deltaT, BC, xsT, al, dp, zT, cdT, Hbuf, Sbuf);
        scan2_k<<<(BB*DI)/4, 256, 0, stream>>>(Hbuf, Sbuf, al, h0buf);
        scan3_k<<<(BB*DI*NCH)/4, 256, 0, stream>>>(
            zT, cdT, rT, xdblT, al, h0buf, yT_bf);
        trans_y_k<<<dim3(WLEN/64, DI/64, BB), 256, 0, stream>>>(yT_bf, y_bf);

        gemm_bf16<4><<<dim3(TOK/128, DDIM/128), 256, 0, stream>>>(
            y_bf, mow, x, x, nullptr, nullptr, TOK, DDIM, DI);
    }

    // Head (f32)
    gemm_nt<2><<<dim3(TOK/64, 256/64), 256, 0, stream>>>(
        x, DDIM, h1_w, DDIM, h1_b, t1, 256, TOK, 256, DDIM);
    gemm_nt<2><<<dim3(TOK/64, 2), 256, 0, stream>>>(
        t1, 256, h2_w, 256, h2_b, t2, 128, TOK, 128, 256);
    gemm_nt<1><<<dim3(TOK/64, 1), 256, 0, stream>>>(
        t2, 128, h3_w, 128, h3_b, out, NCLS, TOK, NCLS, 128);
}